// Round 16
// baseline (1396.445 us; speedup 1.0000x reference)
//
#include <hip/hip_runtime.h>
#include <hip/hip_bf16.h>
#include <cstdint>
#include <cstdio>

// ---------------------------------------------------------------------------
// GATv2 x3 (shared weights layers 2,3) + global max pool, MI355X.
// R16: gat_fused SOFTWARE-PIPELINED across grid-stride iterations: next
// node's meta (coalesced) + XR row + first rec batch are prefetched while
// the current node computes, overlapping the ~1800-cycle meta->recs->rows
// chain with ~1000 cycles of compute. Double-buffered node state (~+40
// VGPR, capped at 128 via __launch_bounds__(256,4)).
//
// Sorted-CSR (R15): meta[idx]={rp,deg,node} coalesced; recs contiguous at rp.
// Buffers: A = XL, B = XR / H (rotating), both [N][128] bf16.
//   gemm_mfma (K=128): reads H=B rows, writes XL=A + XR=B IN-PLACE (own 64
//     rows; __syncthreads between reads and stores).
// ws ~125 MB (budget 256 MB, checked). No hipMemset* (graph capture).
// ---------------------------------------------------------------------------

typedef __attribute__((ext_vector_type(8))) short bf16x8;           // MFMA frag
typedef __attribute__((ext_vector_type(8))) unsigned short u16x8;   // 16B row chunk
typedef __attribute__((ext_vector_type(4))) float f32x4;

#define TBT_S 132   // padded LDS table stride (bank spread)

static __device__ __forceinline__ float leaky02(float v) { return v > 0.f ? v : 0.2f * v; }
static __device__ __forceinline__ float b2f(unsigned short u) {
    return __uint_as_float(((unsigned)u) << 16);
}
static __device__ __forceinline__ unsigned short f2b(float f) {
    __hip_bfloat16 h = __float2bfloat16(f);
    return *(unsigned short*)&h;
}

// ---------------- consolidated init: zeros + weight packs + feature build ---

__global__ __launch_bounds__(256) void prep_init(
    int* __restrict__ degcnt, int n_degcnt,
    int* __restrict__ outz, int n_out,
    const float* __restrict__ Wl2, const float* __restrict__ Wr2,
    __hip_bfloat16* __restrict__ Wp,
    const float* __restrict__ Wl1, const float* __restrict__ Wr1,
    __hip_bfloat16* __restrict__ Wp1,
    const int* __restrict__ atom_num, const int* __restrict__ atom_arom,
    const float* __restrict__ x_cont, const float* __restrict__ atom_emb,
    const float* __restrict__ bool_emb, __hip_bfloat16* __restrict__ Xf, int N,
    int e_z1, int e_z2, int e_pw, int e_pw1)   // exclusive block-range ends
{
    int b = blockIdx.x;
    if (b < e_z1) {                       // zero degcnt
        int i = b * 256 + threadIdx.x;
        if (i < n_degcnt) degcnt[i] = 0;
    } else if (b < e_z2) {                // zero out
        int i = (b - e_z1) * 256 + threadIdx.x;
        if (i < n_out) outz[i] = 0;
    } else if (b < e_pw) {                // pack W2 (32768 frags)
        int idx = (b - e_z2) * 256 + threadIdx.x;
        int j    = idx & 7;
        int lane = (idx >> 3) & 63;
        int ks   = (idx >> 9) & 3;
        int nt   = idx >> 11;
        int k = ks * 32 + ((lane >> 4) << 3) + j;
        int n = nt * 16 + (lane & 15);
        float v = (n < 128) ? Wl2[k * 128 + n] : Wr2[k * 128 + (n - 128)];
        Wp[idx] = __float2bfloat16(v);
    } else if (b < e_pw1) {               // pack W1 (8192 frags, K pad 26->32)
        int idx = (b - e_pw) * 256 + threadIdx.x;
        int j    = idx & 7;
        int lane = (idx >> 3) & 63;
        int ntc  = idx >> 9;
        int k = ((lane >> 4) << 3) + j;
        int n = ntc * 16 + (lane & 15);
        float v = 0.f;
        if (k < 26) v = (n < 128) ? Wl1[k * 128 + n] : Wr1[k * 128 + (n - 128)];
        Wp1[idx] = __float2bfloat16(v);
    } else {                              // build Xf[N][32]
        int n = (b - e_pw1) * 256 + threadIdx.x;
        if (n >= N) return;
        int an = atom_num[n], am = atom_arom[n];
        unsigned short v[32];
#pragma unroll
        for (int k = 0; k < 16; k++) v[k] = f2b(atom_emb[an * 16 + k]);
#pragma unroll
        for (int k = 0; k < 8; k++)  v[16 + k] = f2b(x_cont[(size_t)n * 8 + k]);
        v[24] = f2b(bool_emb[am * 2]);
        v[25] = f2b(bool_emb[am * 2 + 1]);
#pragma unroll
        for (int k = 26; k < 32; k++) v[k] = 0;
        unsigned short* dst = (unsigned short*)Xf + (size_t)n * 32;
#pragma unroll
        for (int q = 0; q < 4; q++)
            *(u16x8*)(dst + q * 8) = *(const u16x8*)&v[q * 8];
    }
}

// ---------------- prep kernels ----------------

__global__ __launch_bounds__(256) void count_deg(
    const int* __restrict__ dst, int* __restrict__ deg, int E)
{
    int e = blockIdx.x * 256 + threadIdx.x;
    if (e < E) atomicAdd(&deg[dst[e]], 1);
}

// ---- degree counting sort (contention-free) + sorted-CSR layout ----
#define SORT_BLK 1024

__global__ __launch_bounds__(256) void sort_hist(
    const int* __restrict__ deg, int* __restrict__ block_hist, int N)
{
    __shared__ int h[512];
    for (int i = threadIdx.x; i < 512; i += 256) h[i] = 0;
    __syncthreads();
    int base = blockIdx.x * SORT_BLK;
#pragma unroll
    for (int k = 0; k < 4; k++) {
        int n = base + k * 256 + threadIdx.x;
        if (n < N) {
            int d = deg[n]; if (d > 511) d = 511;
            atomicAdd(&h[d], 1);              // LDS atomic, block-local
        }
    }
    __syncthreads();
    for (int i = threadIdx.x; i < 512; i += 256)
        block_hist[blockIdx.x * 512 + i] = h[i];
}

// One block, 512 threads: thread t owns bin t. Column-scan across sort blocks
// (block_hist -> per-block exclusive offsets), then two bin scans:
// bin_base[d] (node positions) and edge_base[d] (edge positions, weight d).
__global__ __launch_bounds__(512) void sort_scan(
    int* __restrict__ block_hist, int* __restrict__ bin_base,
    int* __restrict__ edge_base, int nsb)
{
    __shared__ int s[512];
    int t = threadIdx.x;
    int acc = 0;
    for (int b = 0; b < nsb; b++) {
        int v = block_hist[b * 512 + t];
        block_hist[b * 512 + t] = acc;
        acc += v;
    }
    // scan 1: node counts -> bin_base
    s[t] = acc;
    __syncthreads();
    for (int off = 1; off < 512; off <<= 1) {
        int x = (t >= off) ? s[t - off] : 0;
        __syncthreads();
        s[t] += x;
        __syncthreads();
    }
    bin_base[t] = s[t] - acc;
    __syncthreads();
    // scan 2: edge counts (count*d) -> edge_base
    int ec = acc * t;
    s[t] = ec;
    __syncthreads();
    for (int off = 1; off < 512; off <<= 1) {
        int x = (t >= off) ? s[t - off] : 0;
        __syncthreads();
        s[t] += x;
        __syncthreads();
    }
    edge_base[t] = s[t] - ec;
}

// Scatter: meta[pos] = {rp_sorted, deg, node, 0}; nrp[node] = rp_sorted.
__global__ __launch_bounds__(256) void sort_scatter(
    const int* __restrict__ deg, const int* __restrict__ block_hist,
    const int* __restrict__ bin_base, const int* __restrict__ edge_base,
    int4* __restrict__ meta, int* __restrict__ nrp, int N)
{
    __shared__ int h[512];
    for (int i = threadIdx.x; i < 512; i += 256) h[i] = 0;
    __syncthreads();
    int bs = blockIdx.x;
    int base = bs * SORT_BLK;
#pragma unroll
    for (int k = 0; k < 4; k++) {
        int n = base + k * 256 + threadIdx.x;
        if (n < N) {
            int d = deg[n]; if (d > 511) d = 511;
            int r = atomicAdd(&h[d], 1);      // LDS atomic rank
            int posInBin = block_hist[bs * 512 + d] + r;
            int pos = bin_base[d] + posInBin;
            int rp = edge_base[d] + posInBin * d;
            int4 m; m.x = rp; m.y = d; m.z = n; m.w = 0;
            meta[pos] = m;
            nrp[n] = rp;
        }
    }
}

// Fill sorted CSR with PACKED per-slot records {src, codes, ec_bits, 0}.
__global__ __launch_bounds__(256) void csr_fill(
    const int* __restrict__ src, const int* __restrict__ dst,
    const int* __restrict__ bond_type, const float* __restrict__ edge_cont,
    const int* __restrict__ bond_conj, const int* __restrict__ bond_arom,
    const int* __restrict__ nrp, int* __restrict__ cnt,
    int4* __restrict__ csr_rec, int E)
{
    int e = blockIdx.x * 256 + threadIdx.x;
    if (e >= E) return;
    int d = dst[e];
    int pos = nrp[d] + atomicAdd(&cnt[d], 1);
    int codes = (bond_type[e] & 0xFF) | ((bond_conj[e] & 1) << 8) | ((bond_arom[e] & 1) << 16);
    int4 rec;
    rec.x = src[e];
    rec.y = codes;
    rec.z = __float_as_int(edge_cont[e]);
    rec.w = 0;
    csr_rec[pos] = rec;
}

// ---------------- per-layer kernels ----------------

// Layer-1 GEMM via MFMA, K=32 (single step): Xfeat[N][32] @ Wp1 -> XL|XR.
__global__ __launch_bounds__(256) void gemm_mfma1(
    const __hip_bfloat16* __restrict__ Xf,   // [N][32]
    const __hip_bfloat16* __restrict__ Wp,   // packed frags, 8192 bf16
    const float* __restrict__ bl, const float* __restrict__ br,
    __hip_bfloat16* __restrict__ XL, __hip_bfloat16* __restrict__ XR, int N)
{
    __shared__ unsigned short sT[64 * 256];   // 32 KB output tile
    int lane = threadIdx.x & 63;
    int wave = threadIdx.x >> 6;
    int row0 = blockIdx.x * 64;
    int m_lane = lane & 15;
    int quad = lane >> 4;
    const unsigned short* Xu = (const unsigned short*)Xf;
    const unsigned short* Wu = (const unsigned short*)Wp;

    f32x4 acc[4][4];
#pragma unroll
    for (int mt = 0; mt < 4; mt++)
#pragma unroll
        for (int nt = 0; nt < 4; nt++) acc[mt][nt] = (f32x4){0.f, 0.f, 0.f, 0.f};

    bf16x8 a[4], b[4];
#pragma unroll
    for (int mt = 0; mt < 4; mt++)
        a[mt] = *(const bf16x8*)(Xu + (size_t)(row0 + mt * 16 + m_lane) * 32 + quad * 8);
#pragma unroll
    for (int nt = 0; nt < 4; nt++)
        b[nt] = *(const bf16x8*)(Wu + ((wave * 4 + nt) * 64 + lane) * 8);
#pragma unroll
    for (int mt = 0; mt < 4; mt++)
#pragma unroll
        for (int nt = 0; nt < 4; nt++)
            acc[mt][nt] = __builtin_amdgcn_mfma_f32_16x16x32_bf16(
                a[mt], b[nt], acc[mt][nt], 0, 0, 0);

#pragma unroll
    for (int nt = 0; nt < 4; nt++) {
        int col = wave * 64 + nt * 16 + m_lane;
        float bv = (col < 128) ? bl[col] : br[col - 128];
#pragma unroll
        for (int mt = 0; mt < 4; mt++) {
            int rbase = mt * 16 + quad * 4;
#pragma unroll
            for (int reg = 0; reg < 4; reg++)
                sT[(rbase + reg) * 256 + col] = f2b(acc[mt][nt][reg] + bv);
        }
    }

    __syncthreads();

    unsigned short* XLu = (unsigned short*)XL;
    unsigned short* XRu = (unsigned short*)XR;
    int t = threadIdx.x;
#pragma unroll
    for (int q = 0; q < 4; q++) {
        int s = t * 32 + q * 8;
        int r = s >> 7, c = s & 127;
        *(u16x8*)(XLu + (size_t)(row0 + r) * 128 + c) = *(const u16x8*)&sT[r * 256 + c];
        *(u16x8*)(XRu + (size_t)(row0 + r) * 128 + c) = *(const u16x8*)&sT[r * 256 + 128 + c];
    }
}

// Layers 2/3 GEMM via MFMA (K=128) with LDS-staged coalesced epilogue.
__global__ __launch_bounds__(256) void gemm_mfma(
    const __hip_bfloat16* H,               // [N][128]  (aliases XR)
    const __hip_bfloat16* __restrict__ Wp, // packed frags, 32768 bf16
    const float* __restrict__ bl, const float* __restrict__ br,
    __hip_bfloat16* __restrict__ XL, __hip_bfloat16* XR, int N)
{
    __shared__ unsigned short sT[64 * 256];   // 32 KB output tile
    int lane = threadIdx.x & 63;
    int wave = threadIdx.x >> 6;
    int row0 = blockIdx.x * 64;
    int m_lane = lane & 15;
    int quad = lane >> 4;
    const unsigned short* Hu = (const unsigned short*)H;
    const unsigned short* Wu = (const unsigned short*)Wp;

    f32x4 acc[4][4];
#pragma unroll
    for (int mt = 0; mt < 4; mt++)
#pragma unroll
        for (int nt = 0; nt < 4; nt++) acc[mt][nt] = (f32x4){0.f, 0.f, 0.f, 0.f};

#pragma unroll
    for (int ks = 0; ks < 4; ks++) {
        int koff = ks * 32 + quad * 8;
        bf16x8 a[4], b[4];
#pragma unroll
        for (int mt = 0; mt < 4; mt++)
            a[mt] = *(const bf16x8*)(Hu + (size_t)(row0 + mt * 16 + m_lane) * 128 + koff);
#pragma unroll
        for (int nt = 0; nt < 4; nt++)
            b[nt] = *(const bf16x8*)(Wu + ((((wave * 4 + nt) * 4) + ks) * 64 + lane) * 8);
#pragma unroll
        for (int mt = 0; mt < 4; mt++)
#pragma unroll
            for (int nt = 0; nt < 4; nt++)
                acc[mt][nt] = __builtin_amdgcn_mfma_f32_16x16x32_bf16(
                    a[mt], b[nt], acc[mt][nt], 0, 0, 0);
    }

#pragma unroll
    for (int nt = 0; nt < 4; nt++) {
        int col = wave * 64 + nt * 16 + m_lane;
        float bv = (col < 128) ? bl[col] : br[col - 128];
#pragma unroll
        for (int mt = 0; mt < 4; mt++) {
            int rbase = mt * 16 + quad * 4;
#pragma unroll
            for (int reg = 0; reg < 4; reg++)
                sT[(rbase + reg) * 256 + col] = f2b(acc[mt][nt][reg] + bv);
        }
    }

    __syncthreads();   // also drains all H loads before any XR store

    unsigned short* XLu = (unsigned short*)XL;
    unsigned short* XRu = (unsigned short*)XR;
    int t = threadIdx.x;
#pragma unroll
    for (int q = 0; q < 4; q++) {
        int s = t * 32 + q * 8;            // short index within 64x128 tile
        int r = s >> 7, c = s & 127;
        *(u16x8*)(XLu + (size_t)(row0 + r) * 128 + c) = *(const u16x8*)&sT[r * 256 + c];
        *(u16x8*)(XRu + (size_t)(row0 + r) * 128 + c) = *(const u16x8*)&sT[r * 256 + 128 + c];
    }
}

// FUSED logits + softmax + aggregate, SOFTWARE-PIPELINED over grid-stride:
// next node's meta + XR row + first rec batch prefetched during current
// node's compute. 16-lane sub-waves, 4 nodes/wave, degree-sorted meta.
__global__ __launch_bounds__(256, 4) void gat_fused(
    const int4* __restrict__ meta, const int4* __restrict__ csr_rec,
    const float* __restrict__ bond_emb, const float* __restrict__ bool_emb,
    const __hip_bfloat16* __restrict__ XL, const __hip_bfloat16* XR,
    const float* __restrict__ We,        // [13][128]
    const float* __restrict__ att,       // [128]
    const float* __restrict__ bias,      // [128]
    __hip_bfloat16* OUT, int N)
{
    __shared__ float sTbt[22 * TBT_S];   // bond_emb[bt] @ We[0:8], padded stride
    __shared__ float sTca[4 * TBT_S];    // bool-pair terms
    __shared__ float sW8[128];           // We[8,:]

    for (int i = threadIdx.x; i < 22 * 128; i += 256) {
        int bt = i >> 7, c = i & 127;
        float s = 0.f;
#pragma unroll
        for (int k = 0; k < 8; k++) s = fmaf(bond_emb[bt * 8 + k], We[k * 128 + c], s);
        sTbt[bt * TBT_S + c] = s;
    }
    for (int i = threadIdx.x; i < 4 * 128; i += 256) {
        int idx = i >> 7, c = i & 127;
        int cj = idx >> 1, ar = idx & 1;
        float s = bool_emb[cj * 2]     * We[9 * 128 + c]
                + bool_emb[cj * 2 + 1] * We[10 * 128 + c]
                + bool_emb[ar * 2]     * We[11 * 128 + c]
                + bool_emb[ar * 2 + 1] * We[12 * 128 + c];
        sTca[idx * TBT_S + c] = s;
    }
    if (threadIdx.x < 128) sW8[threadIdx.x] = We[8 * 128 + threadIdx.x];
    __syncthreads();

    int lane = threadIdx.x & 63;
    int wave = threadIdx.x >> 6;
    int sl   = lane & 15;
    int sw   = lane >> 4;
    int cbase = sl * 8;

    float a8[8], bs8[8], w88[8];
    {
        float4 t0 = *(const float4*)&att[cbase],  t1 = *(const float4*)&att[cbase + 4];
        float4 u0 = *(const float4*)&bias[cbase], u1 = *(const float4*)&bias[cbase + 4];
        float4 v0 = *(const float4*)&sW8[cbase],  v1 = *(const float4*)&sW8[cbase + 4];
#pragma unroll
        for (int i = 0; i < 4; i++) {
            a8[i] = (&t0.x)[i];  a8[i + 4] = (&t1.x)[i];
            bs8[i] = (&u0.x)[i]; bs8[i + 4] = (&u1.x)[i];
            w88[i] = (&v0.x)[i]; w88[i + 4] = (&v1.x)[i];
        }
    }

    const unsigned short* XLu = (const unsigned short*)XL;
    const unsigned short* XRu = (const unsigned short*)XR;
    unsigned short* OUTu = (unsigned short*)OUT;

    int group = (blockIdx.x * 4 + wave) * 4 + sw;   // global sub-wave id
    int stride = gridDim.x * 16;

    // ---- pipeline prologue: load state for first node ----
    int4 mt;
    int4 recs[4];
    u16x8 xru;
    {
        int safe = (group < N) ? group : 0;
        mt = meta[safe];
        xru = *(const u16x8*)(XRu + (size_t)mt.z * 128 + cbase);
        int c0 = mt.y < 4 ? mt.y : 4;
#pragma unroll
        for (int jj = 0; jj < 4; jj++)
            if (jj < c0) recs[jj] = csr_rec[mt.x + jj];
    }

    for (int idx = group; idx < N; idx += stride) {
        int rp = mt.x, dg = mt.y, n = mt.z;
        int cnt0 = dg < 4 ? dg : 4;

        // issue current first-batch row gathers
        u16x8 uv[4];
#pragma unroll
        for (int jj = 0; jj < 4; jj++)
            if (jj < cnt0)
                uv[jj] = *(const u16x8*)(XLu + (size_t)recs[jj].x * 128 + cbase);
        // self-loop row (also needed this iteration)
        u16x8 un = *(const u16x8*)(XLu + (size_t)n * 128 + cbase);

        // prefetch NEXT node's state (meta -> xr + first recs)
        int nidx = idx + stride;
        int nsafe = (nidx < N) ? nidx : 0;
        int4 mt_n = meta[nsafe];
        u16x8 xru_n = *(const u16x8*)(XRu + (size_t)mt_n.z * 128 + cbase);
        int4 recs_n[4];
        int cn = mt_n.y < 4 ? mt_n.y : 4;
#pragma unroll
        for (int jj = 0; jj < 4; jj++)
            if (jj < cn) recs_n[jj] = csr_rec[mt_n.x + jj];

        float xr[8];
#pragma unroll
        for (int i = 0; i < 8; i++) xr[i] = b2f(xru[i]);

        float runs = 0.f;
        float acc[8], ets[8];
#pragma unroll
        for (int i = 0; i < 8; i++) { acc[i] = 0.f; ets[i] = 0.f; }

        // ---- first batch (prefetched recs + uv) ----
        {
            float part[4];
#pragma unroll
            for (int jj = 0; jj < 4; jj++) {
                if (jj >= cnt0) continue;
                int bt = recs[jj].y & 0xFF;
                int ca = (((recs[jj].y >> 8) & 1) << 1) | ((recs[jj].y >> 16) & 1);
                float ec = __int_as_float(recs[jj].z);
                const float* tb = &sTbt[bt * TBT_S + cbase];
                const float* tc = &sTca[ca * TBT_S + cbase];
                float p = 0.f;
#pragma unroll
                for (int i = 0; i < 8; i++) {
                    float et = fmaf(ec, w88[i], tb[i] + tc[i]);
                    ets[i] += et;
                    float m = leaky02(xr[i] + b2f(uv[jj][i]) + et);
                    p = fmaf(m, a8[i], p);
                }
                p += __shfl_xor(p, 1);
                p += __shfl_xor(p, 2);
                p += __shfl_xor(p, 4);
                p += __shfl_xor(p, 8);
                part[jj] = p;
            }
#pragma unroll
            for (int jj = 0; jj < 4; jj++) {
                if (jj >= cnt0) continue;
                float wgt = __expf(part[jj]);
                runs += wgt;
#pragma unroll
                for (int i = 0; i < 8; i++)
                    acc[i] = fmaf(wgt, b2f(uv[jj][i]), acc[i]);
            }
        }

        // ---- remaining batches (inline loads; rare, degree-sorted) ----
        for (int j = 4; j < dg; j += 4) {
            int cnt = dg - j; if (cnt > 4) cnt = 4;
            int4 rec2[4];
#pragma unroll
            for (int jj = 0; jj < 4; jj++)
                if (jj < cnt) rec2[jj] = csr_rec[rp + j + jj];
            u16x8 uv2[4];
#pragma unroll
            for (int jj = 0; jj < 4; jj++)
                if (jj < cnt)
                    uv2[jj] = *(const u16x8*)(XLu + (size_t)rec2[jj].x * 128 + cbase);
            float part[4];
#pragma unroll
            for (int jj = 0; jj < 4; jj++) {
                if (jj >= cnt) continue;
                int bt = rec2[jj].y & 0xFF;
                int ca = (((rec2[jj].y >> 8) & 1) << 1) | ((rec2[jj].y >> 16) & 1);
                float ec = __int_as_float(rec2[jj].z);
                const float* tb = &sTbt[bt * TBT_S + cbase];
                const float* tc = &sTca[ca * TBT_S + cbase];
                float p = 0.f;
#pragma unroll
                for (int i = 0; i < 8; i++) {
                    float et = fmaf(ec, w88[i], tb[i] + tc[i]);
                    ets[i] += et;
                    float m = leaky02(xr[i] + b2f(uv2[jj][i]) + et);
                    p = fmaf(m, a8[i], p);
                }
                p += __shfl_xor(p, 1);
                p += __shfl_xor(p, 2);
                p += __shfl_xor(p, 4);
                p += __shfl_xor(p, 8);
                part[jj] = p;
            }
#pragma unroll
            for (int jj = 0; jj < 4; jj++) {
                if (jj >= cnt) continue;
                float wgt = __expf(part[jj]);
                runs += wgt;
#pragma unroll
                for (int i = 0; i < 8; i++)
                    acc[i] = fmaf(wgt, b2f(uv2[jj][i]), acc[i]);
            }
        }

        // ---- self loop: src = n, edge term = mean of incoming edge terms ----
        {
            float invd = 1.f / (float)(dg > 0 ? dg : 1);
            float p = 0.f;
#pragma unroll
            for (int i = 0; i < 8; i++) {
                float m = leaky02(xr[i] + b2f(un[i]) + ets[i] * invd);
                p = fmaf(m, a8[i], p);
            }
            p += __shfl_xor(p, 1);
            p += __shfl_xor(p, 2);
            p += __shfl_xor(p, 4);
            p += __shfl_xor(p, 8);
            float wgt = __expf(p);
            runs += wgt;
#pragma unroll
            for (int i = 0; i < 8; i++)
                acc[i] = fmaf(wgt, b2f(un[i]), acc[i]);
        }

        float inv = 1.f / runs;
        u16x8 o;
#pragma unroll
        for (int i = 0; i < 8; i++)
            o[i] = f2b(fmaxf(fmaf(acc[i], inv, bs8[i]), 0.f));
        *(u16x8*)(OUTu + (size_t)n * 128 + cbase) = o;

        // ---- rotate pipeline state ----
        mt = mt_n;
        xru = xru_n;
#pragma unroll
        for (int jj = 0; jj < 4; jj++) recs[jj] = recs_n[jj];
    }
}

// Global max pool (bf16 H) into fp32 d_out (zeroed; values >= 0 -> int max ok).
__global__ __launch_bounds__(128) void pool_max(
    const __hip_bfloat16* __restrict__ H, const int* __restrict__ batch,
    float* __restrict__ out, int N)
{
    int c = threadIdx.x;
    int n0 = blockIdx.x * 64;
    int nend = n0 + 64; if (nend > N) nend = N;
    const unsigned short* Hu = (const unsigned short*)H;
    int g_cur = -1;
    float acc = 0.f;
    for (int n = n0; n < nend; ++n) {
        int g = batch[n];
        if (g != g_cur) {
            if (g_cur >= 0)
                atomicMax((int*)out + (size_t)g_cur * 128 + c, __float_as_int(acc));
            g_cur = g;
            acc = 0.f;
        }
        acc = fmaxf(acc, b2f(Hu[(size_t)n * 128 + c]));
    }
    if (g_cur >= 0)
        atomicMax((int*)out + (size_t)g_cur * 128 + c, __float_as_int(acc));
}

// ---------------------------------------------------------------------------

static inline size_t align_up(size_t x, size_t a) { return (x + a - 1) & ~(a - 1); }
static inline int cdiv(int a, int b) { return (a + b - 1) / b; }

extern "C" void kernel_launch(void* const* d_in, const int* in_sizes, int n_in,
                              void* d_out, int out_size, void* d_ws, size_t ws_size,
                              hipStream_t stream)
{
    const int N = in_sizes[0];          // 200000 (multiple of 64)
    const int E = in_sizes[3];          // 800000

    const int*   atom_num  = (const int*)d_in[0];
    const int*   atom_arom = (const int*)d_in[1];
    const float* x_cont    = (const float*)d_in[2];
    const int*   bond_type = (const int*)d_in[3];
    const float* edge_cont = (const float*)d_in[4];
    const int*   bond_conj = (const int*)d_in[5];
    const int*   bond_arom = (const int*)d_in[6];
    const int*   e_src     = (const int*)d_in[7];
    const int*   e_dst     = e_src + E;
    const int*   batch     = (const int*)d_in[8];
    const float* atom_emb  = (const float*)d_in[9];
    const float* bond_emb  = (const float*)d_in[10];
    const float* bool_emb  = (const float*)d_in[11];
    const float* Wl1 = (const float*)d_in[12]; const float* bl1 = (const float*)d_in[13];
    const float* Wr1 = (const float*)d_in[14]; const float* br1 = (const float*)d_in[15];
    const float* We1 = (const float*)d_in[16]; const float* att1 = (const float*)d_in[17];
    const float* bias1 = (const float*)d_in[18];
    const float* Wl2 = (const float*)d_in[19]; const float* bl2 = (const float*)d_in[20];
    const float* Wr2 = (const float*)d_in[21]; const float* br2 = (const float*)d_in[22];
    const float* We2 = (const float*)d_in[23]; const float* att2 = (const float*)d_in[24];
    const float* bias2 = (const float*)d_in[25];
    float* out = (float*)d_out;

    const int nsb = cdiv(N, SORT_BLK);  // sort blocks (196)

    // ---- workspace layout (~125 MB; ws_size is 256 MB) ----
    char* w = (char*)d_ws;
    size_t off = 0;
    auto alloc = [&](size_t bytes) {
        void* p = w + off;
        off = align_up(off + bytes, 256);
        return p;
    };
    __hip_bfloat16* A  = (__hip_bfloat16*)alloc((size_t)N * 128 * 2);   // XL
    __hip_bfloat16* B  = (__hip_bfloat16*)alloc((size_t)N * 128 * 2);   // XR / H
    __hip_bfloat16* Xf = (__hip_bfloat16*)alloc((size_t)N * 32 * 2);    // layer-1 feats
    __hip_bfloat16* Wp = (__hip_bfloat16*)alloc((size_t)32768 * 2);     // packed W2
    __hip_bfloat16* Wp1= (__hip_bfloat16*)alloc((size_t)8192 * 2);      // packed W1
    int*   degcnt  = (int*)alloc((size_t)2 * N * 4);
    int*   deg     = degcnt;
    int*   cnt     = degcnt + N;
    int4*  csr_rec = (int4*)alloc((size_t)E * 16);
    int4*  meta    = (int4*)alloc((size_t)N * 16);
    int*   nrp     = (int*)alloc((size_t)N * 4);
    int*   block_hist = (int*)alloc((size_t)nsb * 512 * 4);
    int*   bin_base   = (int*)alloc(512 * 4);
    int*   edge_base  = (int*)alloc(512 * 4);
    size_t required = off;

    fprintf(stderr, "[GNN] ws_size=%zu required=%zu%s\n", ws_size, required,
            ws_size < required ? "  INSUFFICIENT - skipping" : "");
    if (ws_size < required) return;

    // ---- consolidated init (zeros + packs + feature build), one dispatch ----
    int bz1 = cdiv(2 * N, 256);
    int bz2 = cdiv(out_size, 256);
    int bpw = 32768 / 256;
    int bpw1 = 8192 / 256;
    int bbx = cdiv(N, 256);
    int e_z1 = bz1, e_z2 = e_z1 + bz2, e_pw = e_z2 + bpw, e_pw1 = e_pw + bpw1;
    prep_init<<<e_pw1 + bbx, 256, 0, stream>>>(
        degcnt, 2 * N, (int*)out, out_size,
        Wl2, Wr2, Wp, Wl1, Wr1, Wp1,
        atom_num, atom_arom, x_cont, atom_emb, bool_emb, Xf, N,
        e_z1, e_z2, e_pw, e_pw1);

    // ---- prep: degree sort + sorted CSR (5 dispatches after prep_init) ----
    count_deg<<<cdiv(E, 256), 256, 0, stream>>>(e_dst, deg, E);
    sort_hist<<<nsb, 256, 0, stream>>>(deg, block_hist, N);
    sort_scan<<<1, 512, 0, stream>>>(block_hist, bin_base, edge_base, nsb);
    sort_scatter<<<nsb, 256, 0, stream>>>(deg, block_hist, bin_base, edge_base,
                                          meta, nrp, N);
    csr_fill<<<cdiv(E, 256), 256, 0, stream>>>(e_src, e_dst, bond_type, edge_cont,
                                               bond_conj, bond_arom, nrp, cnt,
                                               csr_rec, E);

    const int fused_blocks = 1536;

    // ---- layer 1: Xf -> A(XL), B(XR) via MFMA; fused -> B(H1) ----
    gemm_mfma1<<<N / 64, 256, 0, stream>>>(Xf, Wp1, bl1, br1, A, B, N);
    gat_fused<<<fused_blocks, 256, 0, stream>>>(
        meta, csr_rec, bond_emb, bool_emb, A, B, We1, att1, bias1, B, N);

    // ---- layers 2 and 3 (shared weights): B -> A, B(in-place); fused -> B ----
    for (int layer = 0; layer < 2; ++layer) {
        gemm_mfma<<<N / 64, 256, 0, stream>>>(B, Wp, bl2, br2, A, B, N);
        gat_fused<<<fused_blocks, 256, 0, stream>>>(
            meta, csr_rec, bond_emb, bool_emb, A, B, We2, att2, bias2, B, N);
    }

    // ---- pooling directly into d_out ----
    pool_max<<<cdiv(N, 64), 128, 0, stream>>>(B, batch, out, N);
}

// Round 17
// 723.390 us; speedup vs baseline: 1.9304x; 1.9304x over previous
//
#include <hip/hip_runtime.h>
#include <hip/hip_bf16.h>
#include <cstdint>
#include <cstdio>

// ---------------------------------------------------------------------------
// GATv2 x3 (shared weights layers 2,3) + global max pool, MI355X.
// R17: REVERT of R16's software pipeline. R16 spilled (WRITE_SIZE 50->766MB,
// VALUBusy 13%): pipelined node state (~115 VGPR) exceeded the 128-VGPR cap
// from __launch_bounds__(256,4) -> every prefetch became scratch traffic.
// This file restores R15's proven gat_fused (107us) unchanged.
//
// Sorted-CSR (R15): meta[idx]={rp,deg,node} coalesced; recs contiguous at rp.
// Buffers: A = XL, B = XR / H (rotating), both [N][128] bf16.
//   gemm_mfma (K=128): reads H=B rows, writes XL=A + XR=B IN-PLACE (own 64
//     rows; __syncthreads between reads and stores).
//   gat_fused: meta (coalesced) -> recs -> XL row gathers; XR[n] read,
//     OUT[n]=B written; 16-lane sub-waves, degree-uniform trip counts.
// ws ~125 MB (budget 256 MB, checked). No hipMemset* (graph capture).
// ---------------------------------------------------------------------------

typedef __attribute__((ext_vector_type(8))) short bf16x8;           // MFMA frag
typedef __attribute__((ext_vector_type(8))) unsigned short u16x8;   // 16B row chunk
typedef __attribute__((ext_vector_type(4))) float f32x4;

#define TBT_S 132   // padded LDS table stride (bank spread)

static __device__ __forceinline__ float leaky02(float v) { return v > 0.f ? v : 0.2f * v; }
static __device__ __forceinline__ float b2f(unsigned short u) {
    return __uint_as_float(((unsigned)u) << 16);
}
static __device__ __forceinline__ unsigned short f2b(float f) {
    __hip_bfloat16 h = __float2bfloat16(f);
    return *(unsigned short*)&h;
}

// ---------------- consolidated init: zeros + weight packs + feature build ---

__global__ __launch_bounds__(256) void prep_init(
    int* __restrict__ degcnt, int n_degcnt,
    int* __restrict__ outz, int n_out,
    const float* __restrict__ Wl2, const float* __restrict__ Wr2,
    __hip_bfloat16* __restrict__ Wp,
    const float* __restrict__ Wl1, const float* __restrict__ Wr1,
    __hip_bfloat16* __restrict__ Wp1,
    const int* __restrict__ atom_num, const int* __restrict__ atom_arom,
    const float* __restrict__ x_cont, const float* __restrict__ atom_emb,
    const float* __restrict__ bool_emb, __hip_bfloat16* __restrict__ Xf, int N,
    int e_z1, int e_z2, int e_pw, int e_pw1)   // exclusive block-range ends
{
    int b = blockIdx.x;
    if (b < e_z1) {                       // zero degcnt
        int i = b * 256 + threadIdx.x;
        if (i < n_degcnt) degcnt[i] = 0;
    } else if (b < e_z2) {                // zero out
        int i = (b - e_z1) * 256 + threadIdx.x;
        if (i < n_out) outz[i] = 0;
    } else if (b < e_pw) {                // pack W2 (32768 frags)
        int idx = (b - e_z2) * 256 + threadIdx.x;
        int j    = idx & 7;
        int lane = (idx >> 3) & 63;
        int ks   = (idx >> 9) & 3;
        int nt   = idx >> 11;
        int k = ks * 32 + ((lane >> 4) << 3) + j;
        int n = nt * 16 + (lane & 15);
        float v = (n < 128) ? Wl2[k * 128 + n] : Wr2[k * 128 + (n - 128)];
        Wp[idx] = __float2bfloat16(v);
    } else if (b < e_pw1) {               // pack W1 (8192 frags, K pad 26->32)
        int idx = (b - e_pw) * 256 + threadIdx.x;
        int j    = idx & 7;
        int lane = (idx >> 3) & 63;
        int ntc  = idx >> 9;
        int k = ((lane >> 4) << 3) + j;
        int n = ntc * 16 + (lane & 15);
        float v = 0.f;
        if (k < 26) v = (n < 128) ? Wl1[k * 128 + n] : Wr1[k * 128 + (n - 128)];
        Wp1[idx] = __float2bfloat16(v);
    } else {                              // build Xf[N][32]
        int n = (b - e_pw1) * 256 + threadIdx.x;
        if (n >= N) return;
        int an = atom_num[n], am = atom_arom[n];
        unsigned short v[32];
#pragma unroll
        for (int k = 0; k < 16; k++) v[k] = f2b(atom_emb[an * 16 + k]);
#pragma unroll
        for (int k = 0; k < 8; k++)  v[16 + k] = f2b(x_cont[(size_t)n * 8 + k]);
        v[24] = f2b(bool_emb[am * 2]);
        v[25] = f2b(bool_emb[am * 2 + 1]);
#pragma unroll
        for (int k = 26; k < 32; k++) v[k] = 0;
        unsigned short* dst = (unsigned short*)Xf + (size_t)n * 32;
#pragma unroll
        for (int q = 0; q < 4; q++)
            *(u16x8*)(dst + q * 8) = *(const u16x8*)&v[q * 8];
    }
}

// ---------------- prep kernels ----------------

__global__ __launch_bounds__(256) void count_deg(
    const int* __restrict__ dst, int* __restrict__ deg, int E)
{
    int e = blockIdx.x * 256 + threadIdx.x;
    if (e < E) atomicAdd(&deg[dst[e]], 1);
}

// ---- degree counting sort (contention-free) + sorted-CSR layout ----
#define SORT_BLK 1024

__global__ __launch_bounds__(256) void sort_hist(
    const int* __restrict__ deg, int* __restrict__ block_hist, int N)
{
    __shared__ int h[512];
    for (int i = threadIdx.x; i < 512; i += 256) h[i] = 0;
    __syncthreads();
    int base = blockIdx.x * SORT_BLK;
#pragma unroll
    for (int k = 0; k < 4; k++) {
        int n = base + k * 256 + threadIdx.x;
        if (n < N) {
            int d = deg[n]; if (d > 511) d = 511;
            atomicAdd(&h[d], 1);              // LDS atomic, block-local
        }
    }
    __syncthreads();
    for (int i = threadIdx.x; i < 512; i += 256)
        block_hist[blockIdx.x * 512 + i] = h[i];
}

// One block, 512 threads: thread t owns bin t. Column-scan across sort blocks
// (block_hist -> per-block exclusive offsets), then two bin scans:
// bin_base[d] (node positions) and edge_base[d] (edge positions, weight d).
__global__ __launch_bounds__(512) void sort_scan(
    int* __restrict__ block_hist, int* __restrict__ bin_base,
    int* __restrict__ edge_base, int nsb)
{
    __shared__ int s[512];
    int t = threadIdx.x;
    int acc = 0;
    for (int b = 0; b < nsb; b++) {
        int v = block_hist[b * 512 + t];
        block_hist[b * 512 + t] = acc;
        acc += v;
    }
    // scan 1: node counts -> bin_base
    s[t] = acc;
    __syncthreads();
    for (int off = 1; off < 512; off <<= 1) {
        int x = (t >= off) ? s[t - off] : 0;
        __syncthreads();
        s[t] += x;
        __syncthreads();
    }
    bin_base[t] = s[t] - acc;
    __syncthreads();
    // scan 2: edge counts (count*d) -> edge_base
    int ec = acc * t;
    s[t] = ec;
    __syncthreads();
    for (int off = 1; off < 512; off <<= 1) {
        int x = (t >= off) ? s[t - off] : 0;
        __syncthreads();
        s[t] += x;
        __syncthreads();
    }
    edge_base[t] = s[t] - ec;
}

// Scatter: meta[pos] = {rp_sorted, deg, node, 0}; nrp[node] = rp_sorted.
__global__ __launch_bounds__(256) void sort_scatter(
    const int* __restrict__ deg, const int* __restrict__ block_hist,
    const int* __restrict__ bin_base, const int* __restrict__ edge_base,
    int4* __restrict__ meta, int* __restrict__ nrp, int N)
{
    __shared__ int h[512];
    for (int i = threadIdx.x; i < 512; i += 256) h[i] = 0;
    __syncthreads();
    int bs = blockIdx.x;
    int base = bs * SORT_BLK;
#pragma unroll
    for (int k = 0; k < 4; k++) {
        int n = base + k * 256 + threadIdx.x;
        if (n < N) {
            int d = deg[n]; if (d > 511) d = 511;
            int r = atomicAdd(&h[d], 1);      // LDS atomic rank
            int posInBin = block_hist[bs * 512 + d] + r;
            int pos = bin_base[d] + posInBin;
            int rp = edge_base[d] + posInBin * d;
            int4 m; m.x = rp; m.y = d; m.z = n; m.w = 0;
            meta[pos] = m;
            nrp[n] = rp;
        }
    }
}

// Fill sorted CSR with PACKED per-slot records {src, codes, ec_bits, 0}.
__global__ __launch_bounds__(256) void csr_fill(
    const int* __restrict__ src, const int* __restrict__ dst,
    const int* __restrict__ bond_type, const float* __restrict__ edge_cont,
    const int* __restrict__ bond_conj, const int* __restrict__ bond_arom,
    const int* __restrict__ nrp, int* __restrict__ cnt,
    int4* __restrict__ csr_rec, int E)
{
    int e = blockIdx.x * 256 + threadIdx.x;
    if (e >= E) return;
    int d = dst[e];
    int pos = nrp[d] + atomicAdd(&cnt[d], 1);
    int codes = (bond_type[e] & 0xFF) | ((bond_conj[e] & 1) << 8) | ((bond_arom[e] & 1) << 16);
    int4 rec;
    rec.x = src[e];
    rec.y = codes;
    rec.z = __float_as_int(edge_cont[e]);
    rec.w = 0;
    csr_rec[pos] = rec;
}

// ---------------- per-layer kernels ----------------

// Layer-1 GEMM via MFMA, K=32 (single step): Xfeat[N][32] @ Wp1 -> XL|XR.
__global__ __launch_bounds__(256) void gemm_mfma1(
    const __hip_bfloat16* __restrict__ Xf,   // [N][32]
    const __hip_bfloat16* __restrict__ Wp,   // packed frags, 8192 bf16
    const float* __restrict__ bl, const float* __restrict__ br,
    __hip_bfloat16* __restrict__ XL, __hip_bfloat16* __restrict__ XR, int N)
{
    __shared__ unsigned short sT[64 * 256];   // 32 KB output tile
    int lane = threadIdx.x & 63;
    int wave = threadIdx.x >> 6;
    int row0 = blockIdx.x * 64;
    int m_lane = lane & 15;
    int quad = lane >> 4;
    const unsigned short* Xu = (const unsigned short*)Xf;
    const unsigned short* Wu = (const unsigned short*)Wp;

    f32x4 acc[4][4];
#pragma unroll
    for (int mt = 0; mt < 4; mt++)
#pragma unroll
        for (int nt = 0; nt < 4; nt++) acc[mt][nt] = (f32x4){0.f, 0.f, 0.f, 0.f};

    bf16x8 a[4], b[4];
#pragma unroll
    for (int mt = 0; mt < 4; mt++)
        a[mt] = *(const bf16x8*)(Xu + (size_t)(row0 + mt * 16 + m_lane) * 32 + quad * 8);
#pragma unroll
    for (int nt = 0; nt < 4; nt++)
        b[nt] = *(const bf16x8*)(Wu + ((wave * 4 + nt) * 64 + lane) * 8);
#pragma unroll
    for (int mt = 0; mt < 4; mt++)
#pragma unroll
        for (int nt = 0; nt < 4; nt++)
            acc[mt][nt] = __builtin_amdgcn_mfma_f32_16x16x32_bf16(
                a[mt], b[nt], acc[mt][nt], 0, 0, 0);

#pragma unroll
    for (int nt = 0; nt < 4; nt++) {
        int col = wave * 64 + nt * 16 + m_lane;
        float bv = (col < 128) ? bl[col] : br[col - 128];
#pragma unroll
        for (int mt = 0; mt < 4; mt++) {
            int rbase = mt * 16 + quad * 4;
#pragma unroll
            for (int reg = 0; reg < 4; reg++)
                sT[(rbase + reg) * 256 + col] = f2b(acc[mt][nt][reg] + bv);
        }
    }

    __syncthreads();

    unsigned short* XLu = (unsigned short*)XL;
    unsigned short* XRu = (unsigned short*)XR;
    int t = threadIdx.x;
#pragma unroll
    for (int q = 0; q < 4; q++) {
        int s = t * 32 + q * 8;
        int r = s >> 7, c = s & 127;
        *(u16x8*)(XLu + (size_t)(row0 + r) * 128 + c) = *(const u16x8*)&sT[r * 256 + c];
        *(u16x8*)(XRu + (size_t)(row0 + r) * 128 + c) = *(const u16x8*)&sT[r * 256 + 128 + c];
    }
}

// Layers 2/3 GEMM via MFMA (K=128) with LDS-staged coalesced epilogue.
__global__ __launch_bounds__(256) void gemm_mfma(
    const __hip_bfloat16* H,               // [N][128]  (aliases XR)
    const __hip_bfloat16* __restrict__ Wp, // packed frags, 32768 bf16
    const float* __restrict__ bl, const float* __restrict__ br,
    __hip_bfloat16* __restrict__ XL, __hip_bfloat16* XR, int N)
{
    __shared__ unsigned short sT[64 * 256];   // 32 KB output tile
    int lane = threadIdx.x & 63;
    int wave = threadIdx.x >> 6;
    int row0 = blockIdx.x * 64;
    int m_lane = lane & 15;
    int quad = lane >> 4;
    const unsigned short* Hu = (const unsigned short*)H;
    const unsigned short* Wu = (const unsigned short*)Wp;

    f32x4 acc[4][4];
#pragma unroll
    for (int mt = 0; mt < 4; mt++)
#pragma unroll
        for (int nt = 0; nt < 4; nt++) acc[mt][nt] = (f32x4){0.f, 0.f, 0.f, 0.f};

#pragma unroll
    for (int ks = 0; ks < 4; ks++) {
        int koff = ks * 32 + quad * 8;
        bf16x8 a[4], b[4];
#pragma unroll
        for (int mt = 0; mt < 4; mt++)
            a[mt] = *(const bf16x8*)(Hu + (size_t)(row0 + mt * 16 + m_lane) * 128 + koff);
#pragma unroll
        for (int nt = 0; nt < 4; nt++)
            b[nt] = *(const bf16x8*)(Wu + ((((wave * 4 + nt) * 4) + ks) * 64 + lane) * 8);
#pragma unroll
        for (int mt = 0; mt < 4; mt++)
#pragma unroll
            for (int nt = 0; nt < 4; nt++)
                acc[mt][nt] = __builtin_amdgcn_mfma_f32_16x16x32_bf16(
                    a[mt], b[nt], acc[mt][nt], 0, 0, 0);
    }

#pragma unroll
    for (int nt = 0; nt < 4; nt++) {
        int col = wave * 64 + nt * 16 + m_lane;
        float bv = (col < 128) ? bl[col] : br[col - 128];
#pragma unroll
        for (int mt = 0; mt < 4; mt++) {
            int rbase = mt * 16 + quad * 4;
#pragma unroll
            for (int reg = 0; reg < 4; reg++)
                sT[(rbase + reg) * 256 + col] = f2b(acc[mt][nt][reg] + bv);
        }
    }

    __syncthreads();   // also drains all H loads before any XR store

    unsigned short* XLu = (unsigned short*)XL;
    unsigned short* XRu = (unsigned short*)XR;
    int t = threadIdx.x;
#pragma unroll
    for (int q = 0; q < 4; q++) {
        int s = t * 32 + q * 8;            // short index within 64x128 tile
        int r = s >> 7, c = s & 127;
        *(u16x8*)(XLu + (size_t)(row0 + r) * 128 + c) = *(const u16x8*)&sT[r * 256 + c];
        *(u16x8*)(XRu + (size_t)(row0 + r) * 128 + c) = *(const u16x8*)&sT[r * 256 + 128 + c];
    }
}

// FUSED logits + softmax + aggregate. 16-lane sub-waves, 4 nodes/wave.
// Sorted-CSR: meta[idx] = {rp, deg, node} is ONE coalesced load; recs are
// contiguous at rp. Softmax without running max (logits bounded, fp32 safe).
__global__ __launch_bounds__(256) void gat_fused(
    const int4* __restrict__ meta, const int4* __restrict__ csr_rec,
    const float* __restrict__ bond_emb, const float* __restrict__ bool_emb,
    const __hip_bfloat16* __restrict__ XL, const __hip_bfloat16* XR,
    const float* __restrict__ We,        // [13][128]
    const float* __restrict__ att,       // [128]
    const float* __restrict__ bias,      // [128]
    __hip_bfloat16* OUT, int N)
{
    __shared__ float sTbt[22 * TBT_S];   // bond_emb[bt] @ We[0:8], padded stride
    __shared__ float sTca[4 * TBT_S];    // bool-pair terms
    __shared__ float sW8[128];           // We[8,:]

    for (int i = threadIdx.x; i < 22 * 128; i += 256) {
        int bt = i >> 7, c = i & 127;
        float s = 0.f;
#pragma unroll
        for (int k = 0; k < 8; k++) s = fmaf(bond_emb[bt * 8 + k], We[k * 128 + c], s);
        sTbt[bt * TBT_S + c] = s;
    }
    for (int i = threadIdx.x; i < 4 * 128; i += 256) {
        int idx = i >> 7, c = i & 127;
        int cj = idx >> 1, ar = idx & 1;
        float s = bool_emb[cj * 2]     * We[9 * 128 + c]
                + bool_emb[cj * 2 + 1] * We[10 * 128 + c]
                + bool_emb[ar * 2]     * We[11 * 128 + c]
                + bool_emb[ar * 2 + 1] * We[12 * 128 + c];
        sTca[idx * TBT_S + c] = s;
    }
    if (threadIdx.x < 128) sW8[threadIdx.x] = We[8 * 128 + threadIdx.x];
    __syncthreads();

    int lane = threadIdx.x & 63;
    int wave = threadIdx.x >> 6;
    int sl   = lane & 15;
    int sw   = lane >> 4;
    int cbase = sl * 8;

    float a8[8], bs8[8], w88[8];
    {
        float4 t0 = *(const float4*)&att[cbase],  t1 = *(const float4*)&att[cbase + 4];
        float4 u0 = *(const float4*)&bias[cbase], u1 = *(const float4*)&bias[cbase + 4];
        float4 v0 = *(const float4*)&sW8[cbase],  v1 = *(const float4*)&sW8[cbase + 4];
#pragma unroll
        for (int i = 0; i < 4; i++) {
            a8[i] = (&t0.x)[i];  a8[i + 4] = (&t1.x)[i];
            bs8[i] = (&u0.x)[i]; bs8[i + 4] = (&u1.x)[i];
            w88[i] = (&v0.x)[i]; w88[i + 4] = (&v1.x)[i];
        }
    }

    const unsigned short* XLu = (const unsigned short*)XL;
    const unsigned short* XRu = (const unsigned short*)XR;
    unsigned short* OUTu = (unsigned short*)OUT;

    int group = (blockIdx.x * 4 + wave) * 4 + sw;   // global sub-wave id
    int stride = gridDim.x * 16;
    for (int idx = group; idx < N; idx += stride) {
        int4 mt = meta[idx];                         // coalesced
        int rp = mt.x, dg = mt.y, n = mt.z;
        u16x8 uxr = *(const u16x8*)(XRu + (size_t)n * 128 + cbase);
        float xr[8];
#pragma unroll
        for (int i = 0; i < 8; i++) xr[i] = b2f(uxr[i]);

        float runs = 0.f;
        float acc[8], ets[8];
#pragma unroll
        for (int i = 0; i < 8; i++) { acc[i] = 0.f; ets[i] = 0.f; }

        for (int j = 0; j < dg; j += 4) {
            int cnt = dg - j; if (cnt > 4) cnt = 4;
            int4 rec[4];
#pragma unroll
            for (int jj = 0; jj < 4; jj++)
                if (jj < cnt) rec[jj] = csr_rec[rp + j + jj];
            u16x8 uv[4];
#pragma unroll
            for (int jj = 0; jj < 4; jj++)
                if (jj < cnt)
                    uv[jj] = *(const u16x8*)(XLu + (size_t)rec[jj].x * 128 + cbase);

            float part[4];
#pragma unroll
            for (int jj = 0; jj < 4; jj++) {
                if (jj >= cnt) continue;
                int bt = rec[jj].y & 0xFF;
                int ca = (((rec[jj].y >> 8) & 1) << 1) | ((rec[jj].y >> 16) & 1);
                float ec = __int_as_float(rec[jj].z);
                const float* tb = &sTbt[bt * TBT_S + cbase];
                const float* tc = &sTca[ca * TBT_S + cbase];
                float p = 0.f;
#pragma unroll
                for (int i = 0; i < 8; i++) {
                    float et = fmaf(ec, w88[i], tb[i] + tc[i]);
                    ets[i] += et;
                    float m = leaky02(xr[i] + b2f(uv[jj][i]) + et);
                    p = fmaf(m, a8[i], p);
                }
                p += __shfl_xor(p, 1);
                p += __shfl_xor(p, 2);
                p += __shfl_xor(p, 4);
                p += __shfl_xor(p, 8);
                part[jj] = p;
            }
#pragma unroll
            for (int jj = 0; jj < 4; jj++) {
                if (jj >= cnt) continue;
                float wgt = __expf(part[jj]);
                runs += wgt;
#pragma unroll
                for (int i = 0; i < 8; i++)
                    acc[i] = fmaf(wgt, b2f(uv[jj][i]), acc[i]);
            }
        }

        {   // self loop: src = n, edge term = mean of incoming edge terms
            u16x8 un = *(const u16x8*)(XLu + (size_t)n * 128 + cbase);
            float invd = 1.f / (float)(dg > 0 ? dg : 1);
            float p = 0.f;
#pragma unroll
            for (int i = 0; i < 8; i++) {
                float m = leaky02(xr[i] + b2f(un[i]) + ets[i] * invd);
                p = fmaf(m, a8[i], p);
            }
            p += __shfl_xor(p, 1);
            p += __shfl_xor(p, 2);
            p += __shfl_xor(p, 4);
            p += __shfl_xor(p, 8);
            float wgt = __expf(p);
            runs += wgt;
#pragma unroll
            for (int i = 0; i < 8; i++)
                acc[i] = fmaf(wgt, b2f(un[i]), acc[i]);
        }

        float inv = 1.f / runs;
        u16x8 o;
#pragma unroll
        for (int i = 0; i < 8; i++)
            o[i] = f2b(fmaxf(fmaf(acc[i], inv, bs8[i]), 0.f));
        *(u16x8*)(OUTu + (size_t)n * 128 + cbase) = o;
    }
}

// Global max pool (bf16 H) into fp32 d_out (zeroed; values >= 0 -> int max ok).
__global__ __launch_bounds__(128) void pool_max(
    const __hip_bfloat16* __restrict__ H, const int* __restrict__ batch,
    float* __restrict__ out, int N)
{
    int c = threadIdx.x;
    int n0 = blockIdx.x * 64;
    int nend = n0 + 64; if (nend > N) nend = N;
    const unsigned short* Hu = (const unsigned short*)H;
    int g_cur = -1;
    float acc = 0.f;
    for (int n = n0; n < nend; ++n) {
        int g = batch[n];
        if (g != g_cur) {
            if (g_cur >= 0)
                atomicMax((int*)out + (size_t)g_cur * 128 + c, __float_as_int(acc));
            g_cur = g;
            acc = 0.f;
        }
        acc = fmaxf(acc, b2f(Hu[(size_t)n * 128 + c]));
    }
    if (g_cur >= 0)
        atomicMax((int*)out + (size_t)g_cur * 128 + c, __float_as_int(acc));
}

// ---------------------------------------------------------------------------

static inline size_t align_up(size_t x, size_t a) { return (x + a - 1) & ~(a - 1); }
static inline int cdiv(int a, int b) { return (a + b - 1) / b; }

extern "C" void kernel_launch(void* const* d_in, const int* in_sizes, int n_in,
                              void* d_out, int out_size, void* d_ws, size_t ws_size,
                              hipStream_t stream)
{
    const int N = in_sizes[0];          // 200000 (multiple of 64)
    const int E = in_sizes[3];          // 800000

    const int*   atom_num  = (const int*)d_in[0];
    const int*   atom_arom = (const int*)d_in[1];
    const float* x_cont    = (const float*)d_in[2];
    const int*   bond_type = (const int*)d_in[3];
    const float* edge_cont = (const float*)d_in[4];
    const int*   bond_conj = (const int*)d_in[5];
    const int*   bond_arom = (const int*)d_in[6];
    const int*   e_src     = (const int*)d_in[7];
    const int*   e_dst     = e_src + E;
    const int*   batch     = (const int*)d_in[8];
    const float* atom_emb  = (const float*)d_in[9];
    const float* bond_emb  = (const float*)d_in[10];
    const float* bool_emb  = (const float*)d_in[11];
    const float* Wl1 = (const float*)d_in[12]; const float* bl1 = (const float*)d_in[13];
    const float* Wr1 = (const float*)d_in[14]; const float* br1 = (const float*)d_in[15];
    const float* We1 = (const float*)d_in[16]; const float* att1 = (const float*)d_in[17];
    const float* bias1 = (const float*)d_in[18];
    const float* Wl2 = (const float*)d_in[19]; const float* bl2 = (const float*)d_in[20];
    const float* Wr2 = (const float*)d_in[21]; const float* br2 = (const float*)d_in[22];
    const float* We2 = (const float*)d_in[23]; const float* att2 = (const float*)d_in[24];
    const float* bias2 = (const float*)d_in[25];
    float* out = (float*)d_out;

    const int nsb = cdiv(N, SORT_BLK);  // sort blocks (196)

    // ---- workspace layout (~125 MB; ws_size is 256 MB) ----
    char* w = (char*)d_ws;
    size_t off = 0;
    auto alloc = [&](size_t bytes) {
        void* p = w + off;
        off = align_up(off + bytes, 256);
        return p;
    };
    __hip_bfloat16* A  = (__hip_bfloat16*)alloc((size_t)N * 128 * 2);   // XL
    __hip_bfloat16* B  = (__hip_bfloat16*)alloc((size_t)N * 128 * 2);   // XR / H
    __hip_bfloat16* Xf = (__hip_bfloat16*)alloc((size_t)N * 32 * 2);    // layer-1 feats
    __hip_bfloat16* Wp = (__hip_bfloat16*)alloc((size_t)32768 * 2);     // packed W2
    __hip_bfloat16* Wp1= (__hip_bfloat16*)alloc((size_t)8192 * 2);      // packed W1
    int*   degcnt  = (int*)alloc((size_t)2 * N * 4);
    int*   deg     = degcnt;
    int*   cnt     = degcnt + N;
    int4*  csr_rec = (int4*)alloc((size_t)E * 16);
    int4*  meta    = (int4*)alloc((size_t)N * 16);
    int*   nrp     = (int*)alloc((size_t)N * 4);
    int*   block_hist = (int*)alloc((size_t)nsb * 512 * 4);
    int*   bin_base   = (int*)alloc(512 * 4);
    int*   edge_base  = (int*)alloc(512 * 4);
    size_t required = off;

    fprintf(stderr, "[GNN] ws_size=%zu required=%zu%s\n", ws_size, required,
            ws_size < required ? "  INSUFFICIENT - skipping" : "");
    if (ws_size < required) return;

    // ---- consolidated init (zeros + packs + feature build), one dispatch ----
    int bz1 = cdiv(2 * N, 256);
    int bz2 = cdiv(out_size, 256);
    int bpw = 32768 / 256;
    int bpw1 = 8192 / 256;
    int bbx = cdiv(N, 256);
    int e_z1 = bz1, e_z2 = e_z1 + bz2, e_pw = e_z2 + bpw, e_pw1 = e_pw + bpw1;
    prep_init<<<e_pw1 + bbx, 256, 0, stream>>>(
        degcnt, 2 * N, (int*)out, out_size,
        Wl2, Wr2, Wp, Wl1, Wr1, Wp1,
        atom_num, atom_arom, x_cont, atom_emb, bool_emb, Xf, N,
        e_z1, e_z2, e_pw, e_pw1);

    // ---- prep: degree sort + sorted CSR (5 dispatches after prep_init) ----
    count_deg<<<cdiv(E, 256), 256, 0, stream>>>(e_dst, deg, E);
    sort_hist<<<nsb, 256, 0, stream>>>(deg, block_hist, N);
    sort_scan<<<1, 512, 0, stream>>>(block_hist, bin_base, edge_base, nsb);
    sort_scatter<<<nsb, 256, 0, stream>>>(deg, block_hist, bin_base, edge_base,
                                          meta, nrp, N);
    csr_fill<<<cdiv(E, 256), 256, 0, stream>>>(e_src, e_dst, bond_type, edge_cont,
                                               bond_conj, bond_arom, nrp, cnt,
                                               csr_rec, E);

    const int fused_blocks = 1536;

    // ---- layer 1: Xf -> A(XL), B(XR) via MFMA; fused -> B(H1) ----
    gemm_mfma1<<<N / 64, 256, 0, stream>>>(Xf, Wp1, bl1, br1, A, B, N);
    gat_fused<<<fused_blocks, 256, 0, stream>>>(
        meta, csr_rec, bond_emb, bool_emb, A, B, We1, att1, bias1, B, N);

    // ---- layers 2 and 3 (shared weights): B -> A, B(in-place); fused -> B ----
    for (int layer = 0; layer < 2; ++layer) {
        gemm_mfma<<<N / 64, 256, 0, stream>>>(B, Wp, bl2, br2, A, B, N);
        gat_fused<<<fused_blocks, 256, 0, stream>>>(
            meta, csr_rec, bond_emb, bool_emb, A, B, We2, att2, bias2, B, N);
    }

    // ---- pooling directly into d_out ----
    pool_max<<<cdiv(N, 64), 128, 0, stream>>>(B, batch, out, N);
}

// Round 18
// 713.491 us; speedup vs baseline: 1.9572x; 1.0139x over previous
//
#include <hip/hip_runtime.h>
#include <hip/hip_bf16.h>
#include <cstdint>
#include <cstdio>

// ---------------------------------------------------------------------------
// GATv2 x3 (shared weights layers 2,3) + global max pool, MI355X.
// R18: two LOW-REGISTER latency hoists in gat_fused (anti-R16; <= +8 VGPR):
//   (1) self-loop row load un=XL[n] hoisted to the top of the node iteration
//       (was a serial ~900-cycle tail stall after the slot loop);
//   (2) meta[idx+stride] prefetched (one coalesced 16B load) to hide the
//       ~300-cycle meta latency heading the next iteration's chain.
// Everything else identical to R17 (proven 723us).
//
// Sorted-CSR (R15): meta[idx]={rp,deg,node} coalesced; recs contiguous at rp.
// Buffers: A = XL, B = XR / H (rotating), both [N][128] bf16.
//   gemm_mfma (K=128): reads H=B rows, writes XL=A + XR=B IN-PLACE (own 64
//     rows; __syncthreads between reads and stores).
// ws ~125 MB (budget 256 MB, checked). No hipMemset* (graph capture).
// ---------------------------------------------------------------------------

typedef __attribute__((ext_vector_type(8))) short bf16x8;           // MFMA frag
typedef __attribute__((ext_vector_type(8))) unsigned short u16x8;   // 16B row chunk
typedef __attribute__((ext_vector_type(4))) float f32x4;

#define TBT_S 132   // padded LDS table stride (bank spread)

static __device__ __forceinline__ float leaky02(float v) { return v > 0.f ? v : 0.2f * v; }
static __device__ __forceinline__ float b2f(unsigned short u) {
    return __uint_as_float(((unsigned)u) << 16);
}
static __device__ __forceinline__ unsigned short f2b(float f) {
    __hip_bfloat16 h = __float2bfloat16(f);
    return *(unsigned short*)&h;
}

// ---------------- consolidated init: zeros + weight packs + feature build ---

__global__ __launch_bounds__(256) void prep_init(
    int* __restrict__ degcnt, int n_degcnt,
    int* __restrict__ outz, int n_out,
    const float* __restrict__ Wl2, const float* __restrict__ Wr2,
    __hip_bfloat16* __restrict__ Wp,
    const float* __restrict__ Wl1, const float* __restrict__ Wr1,
    __hip_bfloat16* __restrict__ Wp1,
    const int* __restrict__ atom_num, const int* __restrict__ atom_arom,
    const float* __restrict__ x_cont, const float* __restrict__ atom_emb,
    const float* __restrict__ bool_emb, __hip_bfloat16* __restrict__ Xf, int N,
    int e_z1, int e_z2, int e_pw, int e_pw1)   // exclusive block-range ends
{
    int b = blockIdx.x;
    if (b < e_z1) {                       // zero degcnt
        int i = b * 256 + threadIdx.x;
        if (i < n_degcnt) degcnt[i] = 0;
    } else if (b < e_z2) {                // zero out
        int i = (b - e_z1) * 256 + threadIdx.x;
        if (i < n_out) outz[i] = 0;
    } else if (b < e_pw) {                // pack W2 (32768 frags)
        int idx = (b - e_z2) * 256 + threadIdx.x;
        int j    = idx & 7;
        int lane = (idx >> 3) & 63;
        int ks   = (idx >> 9) & 3;
        int nt   = idx >> 11;
        int k = ks * 32 + ((lane >> 4) << 3) + j;
        int n = nt * 16 + (lane & 15);
        float v = (n < 128) ? Wl2[k * 128 + n] : Wr2[k * 128 + (n - 128)];
        Wp[idx] = __float2bfloat16(v);
    } else if (b < e_pw1) {               // pack W1 (8192 frags, K pad 26->32)
        int idx = (b - e_pw) * 256 + threadIdx.x;
        int j    = idx & 7;
        int lane = (idx >> 3) & 63;
        int ntc  = idx >> 9;
        int k = ((lane >> 4) << 3) + j;
        int n = ntc * 16 + (lane & 15);
        float v = 0.f;
        if (k < 26) v = (n < 128) ? Wl1[k * 128 + n] : Wr1[k * 128 + (n - 128)];
        Wp1[idx] = __float2bfloat16(v);
    } else {                              // build Xf[N][32]
        int n = (b - e_pw1) * 256 + threadIdx.x;
        if (n >= N) return;
        int an = atom_num[n], am = atom_arom[n];
        unsigned short v[32];
#pragma unroll
        for (int k = 0; k < 16; k++) v[k] = f2b(atom_emb[an * 16 + k]);
#pragma unroll
        for (int k = 0; k < 8; k++)  v[16 + k] = f2b(x_cont[(size_t)n * 8 + k]);
        v[24] = f2b(bool_emb[am * 2]);
        v[25] = f2b(bool_emb[am * 2 + 1]);
#pragma unroll
        for (int k = 26; k < 32; k++) v[k] = 0;
        unsigned short* dst = (unsigned short*)Xf + (size_t)n * 32;
#pragma unroll
        for (int q = 0; q < 4; q++)
            *(u16x8*)(dst + q * 8) = *(const u16x8*)&v[q * 8];
    }
}

// ---------------- prep kernels ----------------

__global__ __launch_bounds__(256) void count_deg(
    const int* __restrict__ dst, int* __restrict__ deg, int E)
{
    int e = blockIdx.x * 256 + threadIdx.x;
    if (e < E) atomicAdd(&deg[dst[e]], 1);
}

// ---- degree counting sort (contention-free) + sorted-CSR layout ----
#define SORT_BLK 1024

__global__ __launch_bounds__(256) void sort_hist(
    const int* __restrict__ deg, int* __restrict__ block_hist, int N)
{
    __shared__ int h[512];
    for (int i = threadIdx.x; i < 512; i += 256) h[i] = 0;
    __syncthreads();
    int base = blockIdx.x * SORT_BLK;
#pragma unroll
    for (int k = 0; k < 4; k++) {
        int n = base + k * 256 + threadIdx.x;
        if (n < N) {
            int d = deg[n]; if (d > 511) d = 511;
            atomicAdd(&h[d], 1);              // LDS atomic, block-local
        }
    }
    __syncthreads();
    for (int i = threadIdx.x; i < 512; i += 256)
        block_hist[blockIdx.x * 512 + i] = h[i];
}

// One block, 512 threads: thread t owns bin t. Column-scan across sort blocks
// (block_hist -> per-block exclusive offsets), then two bin scans:
// bin_base[d] (node positions) and edge_base[d] (edge positions, weight d).
__global__ __launch_bounds__(512) void sort_scan(
    int* __restrict__ block_hist, int* __restrict__ bin_base,
    int* __restrict__ edge_base, int nsb)
{
    __shared__ int s[512];
    int t = threadIdx.x;
    int acc = 0;
    for (int b = 0; b < nsb; b++) {
        int v = block_hist[b * 512 + t];
        block_hist[b * 512 + t] = acc;
        acc += v;
    }
    // scan 1: node counts -> bin_base
    s[t] = acc;
    __syncthreads();
    for (int off = 1; off < 512; off <<= 1) {
        int x = (t >= off) ? s[t - off] : 0;
        __syncthreads();
        s[t] += x;
        __syncthreads();
    }
    bin_base[t] = s[t] - acc;
    __syncthreads();
    // scan 2: edge counts (count*d) -> edge_base
    int ec = acc * t;
    s[t] = ec;
    __syncthreads();
    for (int off = 1; off < 512; off <<= 1) {
        int x = (t >= off) ? s[t - off] : 0;
        __syncthreads();
        s[t] += x;
        __syncthreads();
    }
    edge_base[t] = s[t] - ec;
}

// Scatter: meta[pos] = {rp_sorted, deg, node, 0}; nrp[node] = rp_sorted.
__global__ __launch_bounds__(256) void sort_scatter(
    const int* __restrict__ deg, const int* __restrict__ block_hist,
    const int* __restrict__ bin_base, const int* __restrict__ edge_base,
    int4* __restrict__ meta, int* __restrict__ nrp, int N)
{
    __shared__ int h[512];
    for (int i = threadIdx.x; i < 512; i += 256) h[i] = 0;
    __syncthreads();
    int bs = blockIdx.x;
    int base = bs * SORT_BLK;
#pragma unroll
    for (int k = 0; k < 4; k++) {
        int n = base + k * 256 + threadIdx.x;
        if (n < N) {
            int d = deg[n]; if (d > 511) d = 511;
            int r = atomicAdd(&h[d], 1);      // LDS atomic rank
            int posInBin = block_hist[bs * 512 + d] + r;
            int pos = bin_base[d] + posInBin;
            int rp = edge_base[d] + posInBin * d;
            int4 m; m.x = rp; m.y = d; m.z = n; m.w = 0;
            meta[pos] = m;
            nrp[n] = rp;
        }
    }
}

// Fill sorted CSR with PACKED per-slot records {src, codes, ec_bits, 0}.
__global__ __launch_bounds__(256) void csr_fill(
    const int* __restrict__ src, const int* __restrict__ dst,
    const int* __restrict__ bond_type, const float* __restrict__ edge_cont,
    const int* __restrict__ bond_conj, const int* __restrict__ bond_arom,
    const int* __restrict__ nrp, int* __restrict__ cnt,
    int4* __restrict__ csr_rec, int E)
{
    int e = blockIdx.x * 256 + threadIdx.x;
    if (e >= E) return;
    int d = dst[e];
    int pos = nrp[d] + atomicAdd(&cnt[d], 1);
    int codes = (bond_type[e] & 0xFF) | ((bond_conj[e] & 1) << 8) | ((bond_arom[e] & 1) << 16);
    int4 rec;
    rec.x = src[e];
    rec.y = codes;
    rec.z = __float_as_int(edge_cont[e]);
    rec.w = 0;
    csr_rec[pos] = rec;
}

// ---------------- per-layer kernels ----------------

// Layer-1 GEMM via MFMA, K=32 (single step): Xfeat[N][32] @ Wp1 -> XL|XR.
__global__ __launch_bounds__(256) void gemm_mfma1(
    const __hip_bfloat16* __restrict__ Xf,   // [N][32]
    const __hip_bfloat16* __restrict__ Wp,   // packed frags, 8192 bf16
    const float* __restrict__ bl, const float* __restrict__ br,
    __hip_bfloat16* __restrict__ XL, __hip_bfloat16* __restrict__ XR, int N)
{
    __shared__ unsigned short sT[64 * 256];   // 32 KB output tile
    int lane = threadIdx.x & 63;
    int wave = threadIdx.x >> 6;
    int row0 = blockIdx.x * 64;
    int m_lane = lane & 15;
    int quad = lane >> 4;
    const unsigned short* Xu = (const unsigned short*)Xf;
    const unsigned short* Wu = (const unsigned short*)Wp;

    f32x4 acc[4][4];
#pragma unroll
    for (int mt = 0; mt < 4; mt++)
#pragma unroll
        for (int nt = 0; nt < 4; nt++) acc[mt][nt] = (f32x4){0.f, 0.f, 0.f, 0.f};

    bf16x8 a[4], b[4];
#pragma unroll
    for (int mt = 0; mt < 4; mt++)
        a[mt] = *(const bf16x8*)(Xu + (size_t)(row0 + mt * 16 + m_lane) * 32 + quad * 8);
#pragma unroll
    for (int nt = 0; nt < 4; nt++)
        b[nt] = *(const bf16x8*)(Wu + ((wave * 4 + nt) * 64 + lane) * 8);
#pragma unroll
    for (int mt = 0; mt < 4; mt++)
#pragma unroll
        for (int nt = 0; nt < 4; nt++)
            acc[mt][nt] = __builtin_amdgcn_mfma_f32_16x16x32_bf16(
                a[mt], b[nt], acc[mt][nt], 0, 0, 0);

#pragma unroll
    for (int nt = 0; nt < 4; nt++) {
        int col = wave * 64 + nt * 16 + m_lane;
        float bv = (col < 128) ? bl[col] : br[col - 128];
#pragma unroll
        for (int mt = 0; mt < 4; mt++) {
            int rbase = mt * 16 + quad * 4;
#pragma unroll
            for (int reg = 0; reg < 4; reg++)
                sT[(rbase + reg) * 256 + col] = f2b(acc[mt][nt][reg] + bv);
        }
    }

    __syncthreads();

    unsigned short* XLu = (unsigned short*)XL;
    unsigned short* XRu = (unsigned short*)XR;
    int t = threadIdx.x;
#pragma unroll
    for (int q = 0; q < 4; q++) {
        int s = t * 32 + q * 8;
        int r = s >> 7, c = s & 127;
        *(u16x8*)(XLu + (size_t)(row0 + r) * 128 + c) = *(const u16x8*)&sT[r * 256 + c];
        *(u16x8*)(XRu + (size_t)(row0 + r) * 128 + c) = *(const u16x8*)&sT[r * 256 + 128 + c];
    }
}

// Layers 2/3 GEMM via MFMA (K=128) with LDS-staged coalesced epilogue.
__global__ __launch_bounds__(256) void gemm_mfma(
    const __hip_bfloat16* H,               // [N][128]  (aliases XR)
    const __hip_bfloat16* __restrict__ Wp, // packed frags, 32768 bf16
    const float* __restrict__ bl, const float* __restrict__ br,
    __hip_bfloat16* __restrict__ XL, __hip_bfloat16* XR, int N)
{
    __shared__ unsigned short sT[64 * 256];   // 32 KB output tile
    int lane = threadIdx.x & 63;
    int wave = threadIdx.x >> 6;
    int row0 = blockIdx.x * 64;
    int m_lane = lane & 15;
    int quad = lane >> 4;
    const unsigned short* Hu = (const unsigned short*)H;
    const unsigned short* Wu = (const unsigned short*)Wp;

    f32x4 acc[4][4];
#pragma unroll
    for (int mt = 0; mt < 4; mt++)
#pragma unroll
        for (int nt = 0; nt < 4; nt++) acc[mt][nt] = (f32x4){0.f, 0.f, 0.f, 0.f};

#pragma unroll
    for (int ks = 0; ks < 4; ks++) {
        int koff = ks * 32 + quad * 8;
        bf16x8 a[4], b[4];
#pragma unroll
        for (int mt = 0; mt < 4; mt++)
            a[mt] = *(const bf16x8*)(Hu + (size_t)(row0 + mt * 16 + m_lane) * 128 + koff);
#pragma unroll
        for (int nt = 0; nt < 4; nt++)
            b[nt] = *(const bf16x8*)(Wu + ((((wave * 4 + nt) * 4) + ks) * 64 + lane) * 8);
#pragma unroll
        for (int mt = 0; mt < 4; mt++)
#pragma unroll
            for (int nt = 0; nt < 4; nt++)
                acc[mt][nt] = __builtin_amdgcn_mfma_f32_16x16x32_bf16(
                    a[mt], b[nt], acc[mt][nt], 0, 0, 0);
    }

#pragma unroll
    for (int nt = 0; nt < 4; nt++) {
        int col = wave * 64 + nt * 16 + m_lane;
        float bv = (col < 128) ? bl[col] : br[col - 128];
#pragma unroll
        for (int mt = 0; mt < 4; mt++) {
            int rbase = mt * 16 + quad * 4;
#pragma unroll
            for (int reg = 0; reg < 4; reg++)
                sT[(rbase + reg) * 256 + col] = f2b(acc[mt][nt][reg] + bv);
        }
    }

    __syncthreads();   // also drains all H loads before any XR store

    unsigned short* XLu = (unsigned short*)XL;
    unsigned short* XRu = (unsigned short*)XR;
    int t = threadIdx.x;
#pragma unroll
    for (int q = 0; q < 4; q++) {
        int s = t * 32 + q * 8;            // short index within 64x128 tile
        int r = s >> 7, c = s & 127;
        *(u16x8*)(XLu + (size_t)(row0 + r) * 128 + c) = *(const u16x8*)&sT[r * 256 + c];
        *(u16x8*)(XRu + (size_t)(row0 + r) * 128 + c) = *(const u16x8*)&sT[r * 256 + 128 + c];
    }
}

// FUSED logits + softmax + aggregate. 16-lane sub-waves, 4 nodes/wave.
// R18: self-loop row (un) issued at iteration top (overlaps slot loop);
// next iteration's meta prefetched (one coalesced 16B load only).
__global__ __launch_bounds__(256) void gat_fused(
    const int4* __restrict__ meta, const int4* __restrict__ csr_rec,
    const float* __restrict__ bond_emb, const float* __restrict__ bool_emb,
    const __hip_bfloat16* __restrict__ XL, const __hip_bfloat16* XR,
    const float* __restrict__ We,        // [13][128]
    const float* __restrict__ att,       // [128]
    const float* __restrict__ bias,      // [128]
    __hip_bfloat16* OUT, int N)
{
    __shared__ float sTbt[22 * TBT_S];   // bond_emb[bt] @ We[0:8], padded stride
    __shared__ float sTca[4 * TBT_S];    // bool-pair terms
    __shared__ float sW8[128];           // We[8,:]

    for (int i = threadIdx.x; i < 22 * 128; i += 256) {
        int bt = i >> 7, c = i & 127;
        float s = 0.f;
#pragma unroll
        for (int k = 0; k < 8; k++) s = fmaf(bond_emb[bt * 8 + k], We[k * 128 + c], s);
        sTbt[bt * TBT_S + c] = s;
    }
    for (int i = threadIdx.x; i < 4 * 128; i += 256) {
        int idx = i >> 7, c = i & 127;
        int cj = idx >> 1, ar = idx & 1;
        float s = bool_emb[cj * 2]     * We[9 * 128 + c]
                + bool_emb[cj * 2 + 1] * We[10 * 128 + c]
                + bool_emb[ar * 2]     * We[11 * 128 + c]
                + bool_emb[ar * 2 + 1] * We[12 * 128 + c];
        sTca[idx * TBT_S + c] = s;
    }
    if (threadIdx.x < 128) sW8[threadIdx.x] = We[8 * 128 + threadIdx.x];
    __syncthreads();

    int lane = threadIdx.x & 63;
    int wave = threadIdx.x >> 6;
    int sl   = lane & 15;
    int sw   = lane >> 4;
    int cbase = sl * 8;

    float a8[8], bs8[8], w88[8];
    {
        float4 t0 = *(const float4*)&att[cbase],  t1 = *(const float4*)&att[cbase + 4];
        float4 u0 = *(const float4*)&bias[cbase], u1 = *(const float4*)&bias[cbase + 4];
        float4 v0 = *(const float4*)&sW8[cbase],  v1 = *(const float4*)&sW8[cbase + 4];
#pragma unroll
        for (int i = 0; i < 4; i++) {
            a8[i] = (&t0.x)[i];  a8[i + 4] = (&t1.x)[i];
            bs8[i] = (&u0.x)[i]; bs8[i + 4] = (&u1.x)[i];
            w88[i] = (&v0.x)[i]; w88[i + 4] = (&v1.x)[i];
        }
    }

    const unsigned short* XLu = (const unsigned short*)XL;
    const unsigned short* XRu = (const unsigned short*)XR;
    unsigned short* OUTu = (unsigned short*)OUT;

    int group = (blockIdx.x * 4 + wave) * 4 + sw;   // global sub-wave id
    int stride = gridDim.x * 16;

    int4 mt;
    if (group < N) mt = meta[group];

    for (int idx = group; idx < N; idx += stride) {
        int rp = mt.x, dg = mt.y, n = mt.z;
        // independent loads issued up front: own XR row, self-loop XL row
        u16x8 uxr = *(const u16x8*)(XRu + (size_t)n * 128 + cbase);
        u16x8 un  = *(const u16x8*)(XLu + (size_t)n * 128 + cbase);
        // prefetch next meta (coalesced 16B; only +4 VGPR)
        int nidx = idx + stride;
        int4 mt_n = meta[(nidx < N) ? nidx : idx];

        float xr[8];
#pragma unroll
        for (int i = 0; i < 8; i++) xr[i] = b2f(uxr[i]);

        float runs = 0.f;
        float acc[8], ets[8];
#pragma unroll
        for (int i = 0; i < 8; i++) { acc[i] = 0.f; ets[i] = 0.f; }

        for (int j = 0; j < dg; j += 4) {
            int cnt = dg - j; if (cnt > 4) cnt = 4;
            int4 rec[4];
#pragma unroll
            for (int jj = 0; jj < 4; jj++)
                if (jj < cnt) rec[jj] = csr_rec[rp + j + jj];
            u16x8 uv[4];
#pragma unroll
            for (int jj = 0; jj < 4; jj++)
                if (jj < cnt)
                    uv[jj] = *(const u16x8*)(XLu + (size_t)rec[jj].x * 128 + cbase);

            float part[4];
#pragma unroll
            for (int jj = 0; jj < 4; jj++) {
                if (jj >= cnt) continue;
                int bt = rec[jj].y & 0xFF;
                int ca = (((rec[jj].y >> 8) & 1) << 1) | ((rec[jj].y >> 16) & 1);
                float ec = __int_as_float(rec[jj].z);
                const float* tb = &sTbt[bt * TBT_S + cbase];
                const float* tc = &sTca[ca * TBT_S + cbase];
                float p = 0.f;
#pragma unroll
                for (int i = 0; i < 8; i++) {
                    float et = fmaf(ec, w88[i], tb[i] + tc[i]);
                    ets[i] += et;
                    float m = leaky02(xr[i] + b2f(uv[jj][i]) + et);
                    p = fmaf(m, a8[i], p);
                }
                p += __shfl_xor(p, 1);
                p += __shfl_xor(p, 2);
                p += __shfl_xor(p, 4);
                p += __shfl_xor(p, 8);
                part[jj] = p;
            }
#pragma unroll
            for (int jj = 0; jj < 4; jj++) {
                if (jj >= cnt) continue;
                float wgt = __expf(part[jj]);
                runs += wgt;
#pragma unroll
                for (int i = 0; i < 8; i++)
                    acc[i] = fmaf(wgt, b2f(uv[jj][i]), acc[i]);
            }
        }

        {   // self loop (un already in flight since iteration top)
            float invd = 1.f / (float)(dg > 0 ? dg : 1);
            float p = 0.f;
#pragma unroll
            for (int i = 0; i < 8; i++) {
                float m = leaky02(xr[i] + b2f(un[i]) + ets[i] * invd);
                p = fmaf(m, a8[i], p);
            }
            p += __shfl_xor(p, 1);
            p += __shfl_xor(p, 2);
            p += __shfl_xor(p, 4);
            p += __shfl_xor(p, 8);
            float wgt = __expf(p);
            runs += wgt;
#pragma unroll
            for (int i = 0; i < 8; i++)
                acc[i] = fmaf(wgt, b2f(un[i]), acc[i]);
        }

        float inv = 1.f / runs;
        u16x8 o;
#pragma unroll
        for (int i = 0; i < 8; i++)
            o[i] = f2b(fmaxf(fmaf(acc[i], inv, bs8[i]), 0.f));
        *(u16x8*)(OUTu + (size_t)n * 128 + cbase) = o;

        mt = mt_n;
    }
}

// Global max pool (bf16 H) into fp32 d_out (zeroed; values >= 0 -> int max ok).
__global__ __launch_bounds__(128) void pool_max(
    const __hip_bfloat16* __restrict__ H, const int* __restrict__ batch,
    float* __restrict__ out, int N)
{
    int c = threadIdx.x;
    int n0 = blockIdx.x * 64;
    int nend = n0 + 64; if (nend > N) nend = N;
    const unsigned short* Hu = (const unsigned short*)H;
    int g_cur = -1;
    float acc = 0.f;
    for (int n = n0; n < nend; ++n) {
        int g = batch[n];
        if (g != g_cur) {
            if (g_cur >= 0)
                atomicMax((int*)out + (size_t)g_cur * 128 + c, __float_as_int(acc));
            g_cur = g;
            acc = 0.f;
        }
        acc = fmaxf(acc, b2f(Hu[(size_t)n * 128 + c]));
    }
    if (g_cur >= 0)
        atomicMax((int*)out + (size_t)g_cur * 128 + c, __float_as_int(acc));
}

// ---------------------------------------------------------------------------

static inline size_t align_up(size_t x, size_t a) { return (x + a - 1) & ~(a - 1); }
static inline int cdiv(int a, int b) { return (a + b - 1) / b; }

extern "C" void kernel_launch(void* const* d_in, const int* in_sizes, int n_in,
                              void* d_out, int out_size, void* d_ws, size_t ws_size,
                              hipStream_t stream)
{
    const int N = in_sizes[0];          // 200000 (multiple of 64)
    const int E = in_sizes[3];          // 800000

    const int*   atom_num  = (const int*)d_in[0];
    const int*   atom_arom = (const int*)d_in[1];
    const float* x_cont    = (const float*)d_in[2];
    const int*   bond_type = (const int*)d_in[3];
    const float* edge_cont = (const float*)d_in[4];
    const int*   bond_conj = (const int*)d_in[5];
    const int*   bond_arom = (const int*)d_in[6];
    const int*   e_src     = (const int*)d_in[7];
    const int*   e_dst     = e_src + E;
    const int*   batch     = (const int*)d_in[8];
    const float* atom_emb  = (const float*)d_in[9];
    const float* bond_emb  = (const float*)d_in[10];
    const float* bool_emb  = (const float*)d_in[11];
    const float* Wl1 = (const float*)d_in[12]; const float* bl1 = (const float*)d_in[13];
    const float* Wr1 = (const float*)d_in[14]; const float* br1 = (const float*)d_in[15];
    const float* We1 = (const float*)d_in[16]; const float* att1 = (const float*)d_in[17];
    const float* bias1 = (const float*)d_in[18];
    const float* Wl2 = (const float*)d_in[19]; const float* bl2 = (const float*)d_in[20];
    const float* Wr2 = (const float*)d_in[21]; const float* br2 = (const float*)d_in[22];
    const float* We2 = (const float*)d_in[23]; const float* att2 = (const float*)d_in[24];
    const float* bias2 = (const float*)d_in[25];
    float* out = (float*)d_out;

    const int nsb = cdiv(N, SORT_BLK);  // sort blocks (196)

    // ---- workspace layout (~125 MB; ws_size is 256 MB) ----
    char* w = (char*)d_ws;
    size_t off = 0;
    auto alloc = [&](size_t bytes) {
        void* p = w + off;
        off = align_up(off + bytes, 256);
        return p;
    };
    __hip_bfloat16* A  = (__hip_bfloat16*)alloc((size_t)N * 128 * 2);   // XL
    __hip_bfloat16* B  = (__hip_bfloat16*)alloc((size_t)N * 128 * 2);   // XR / H
    __hip_bfloat16* Xf = (__hip_bfloat16*)alloc((size_t)N * 32 * 2);    // layer-1 feats
    __hip_bfloat16* Wp = (__hip_bfloat16*)alloc((size_t)32768 * 2);     // packed W2
    __hip_bfloat16* Wp1= (__hip_bfloat16*)alloc((size_t)8192 * 2);      // packed W1
    int*   degcnt  = (int*)alloc((size_t)2 * N * 4);
    int*   deg     = degcnt;
    int*   cnt     = degcnt + N;
    int4*  csr_rec = (int4*)alloc((size_t)E * 16);
    int4*  meta    = (int4*)alloc((size_t)N * 16);
    int*   nrp     = (int*)alloc((size_t)N * 4);
    int*   block_hist = (int*)alloc((size_t)nsb * 512 * 4);
    int*   bin_base   = (int*)alloc(512 * 4);
    int*   edge_base  = (int*)alloc(512 * 4);
    size_t required = off;

    fprintf(stderr, "[GNN] ws_size=%zu required=%zu%s\n", ws_size, required,
            ws_size < required ? "  INSUFFICIENT - skipping" : "");
    if (ws_size < required) return;

    // ---- consolidated init (zeros + packs + feature build), one dispatch ----
    int bz1 = cdiv(2 * N, 256);
    int bz2 = cdiv(out_size, 256);
    int bpw = 32768 / 256;
    int bpw1 = 8192 / 256;
    int bbx = cdiv(N, 256);
    int e_z1 = bz1, e_z2 = e_z1 + bz2, e_pw = e_z2 + bpw, e_pw1 = e_pw + bpw1;
    prep_init<<<e_pw1 + bbx, 256, 0, stream>>>(
        degcnt, 2 * N, (int*)out, out_size,
        Wl2, Wr2, Wp, Wl1, Wr1, Wp1,
        atom_num, atom_arom, x_cont, atom_emb, bool_emb, Xf, N,
        e_z1, e_z2, e_pw, e_pw1);

    // ---- prep: degree sort + sorted CSR (5 dispatches after prep_init) ----
    count_deg<<<cdiv(E, 256), 256, 0, stream>>>(e_dst, deg, E);
    sort_hist<<<nsb, 256, 0, stream>>>(deg, block_hist, N);
    sort_scan<<<1, 512, 0, stream>>>(block_hist, bin_base, edge_base, nsb);
    sort_scatter<<<nsb, 256, 0, stream>>>(deg, block_hist, bin_base, edge_base,
                                          meta, nrp, N);
    csr_fill<<<cdiv(E, 256), 256, 0, stream>>>(e_src, e_dst, bond_type, edge_cont,
                                               bond_conj, bond_arom, nrp, cnt,
                                               csr_rec, E);

    const int fused_blocks = 1536;

    // ---- layer 1: Xf -> A(XL), B(XR) via MFMA; fused -> B(H1) ----
    gemm_mfma1<<<N / 64, 256, 0, stream>>>(Xf, Wp1, bl1, br1, A, B, N);
    gat_fused<<<fused_blocks, 256, 0, stream>>>(
        meta, csr_rec, bond_emb, bool_emb, A, B, We1, att1, bias1, B, N);

    // ---- layers 2 and 3 (shared weights): B -> A, B(in-place); fused -> B ----
    for (int layer = 0; layer < 2; ++layer) {
        gemm_mfma<<<N / 64, 256, 0, stream>>>(B, Wp, bl2, br2, A, B, N);
        gat_fused<<<fused_blocks, 256, 0, stream>>>(
            meta, csr_rec, bond_emb, bool_emb, A, B, We2, att2, bias2, B, N);
    }

    // ---- pooling directly into d_out ----
    pool_max<<<cdiv(N, 64), 128, 0, stream>>>(B, batch, out, N);
}